// Round 7
// baseline (251.425 us; speedup 1.0000x reference)
//
#include <hip/hip_runtime.h>
#include <math.h>

// Problem constants (from reference): N=65536 rows, D=512 features, K=5 centroids.
#define LFR_N 65536
#define LFR_D 512
#define LFR_K 5
#define RPW   16                         // rows per wave (one per lane&15)
#define WPB   4                          // waves per block (256 threads)
#define NCH   (LFR_D / 64)               // 8 chunks of 64 d
#define BLOCKS (LFR_N / (RPW * WPB))     // 1024 blocks

// R7: change the LOAD RETURN PATH.
// R0-R6: six structures (VALU -50%, shuffle -60%, prefetch, coalescing shape,
// stream split, inverted parallelism) all pinned at 80-88us / ~2.4 TB/s with
// every pipe idle. In-situ asymmetry: pure WRITE (fillBuffer) = 6.7 TB/s;
// read-dominated streams cap at ~2.0-2.5 TB/s. Remaining mechanism: per-CU
// read-return tracking (TCP line-fill + VGPR writeback) caps outstanding
// lines (~24-32 x 128B / ~375ns = 2.1-2.8 TB/s chip) - writes need no
// return tracking. Untried HIP-visible lever: global_load_lds returns data
// DIRECTLY to LDS (no VGPR round-trip). Keep R6's conflict-free consume;
// stage via 4x1KB global_load_lds per chunk, per-wave double-buffered,
// 2 chunks deep, counted s_waitcnt vmcnt(4) (never 0 until tail).
// LDS dest is forced linear (wave-uniform base + lane*16), so the f4-XOR
// swizzle moves to the GLOBAL source address (rule #21: same involution on
// source and read side); coalescing unaffected (same 256B segments,
// permuted within).

#define LGKM0() do { asm volatile("s_waitcnt lgkmcnt(0)" ::: "memory"); \
                     __builtin_amdgcn_sched_barrier(0); } while (0)
#define WAITVM4() do { asm volatile("s_waitcnt vmcnt(4)" ::: "memory"); \
                       __builtin_amdgcn_sched_barrier(0); } while (0)
#define WAITVM0() do { asm volatile("s_waitcnt vmcnt(0)" ::: "memory"); \
                       __builtin_amdgcn_sched_barrier(0); } while (0)

#define GL2LDS(gaddr, laddr) \
    __builtin_amdgcn_global_load_lds( \
        (const __attribute__((address_space(1))) void*)(gaddr), \
        (__attribute__((address_space(3))) void*)(laddr), 16, 0, 0)

__global__ __launch_bounds__(256) void lfr_kernel(
    const float* __restrict__ x,        // (N, D)
    const float* __restrict__ alpha,    // (D,)
    const float* __restrict__ w,        // (K, 1)
    const float* __restrict__ cent,     // (K, D)
    float* __restrict__ out_map,        // (N, K)
    float* __restrict__ out_rec,        // (N, D)
    float* __restrict__ out_pred)       // (N,)
{
    __shared__ float  sc[LFR_K][LFR_D];     // 10 KB centroids (block-shared)
    __shared__ float  sa[LFR_D];            //  2 KB alpha
    __shared__ float4 sx[WPB][2][16][16];   // 32 KB per-wave double-buffered x tile

    const int tid  = threadIdx.x;
    const int lane = tid & 63;
    const int wib  = tid >> 6;
    const int rr   = lane & 15;          // row-in-tile this lane owns (consume)
    const int qq   = lane >> 4;          // d-quarter (consume) / row-in-group (stage)
    const int ss   = lane & 15;          // f4-slot within stage instruction

    // ---- cooperative stage of cent+alpha (once per block) ----
    {
        const float4* csrc = (const float4*)cent;         // 640 float4
        float4* cdst = (float4*)&sc[0][0];
        #pragma unroll
        for (int i = 0; i < 3; ++i) {
            int idx = tid + i * 256;
            if (idx < (LFR_K * LFR_D) / 4) cdst[idx] = csrc[idx];
        }
        if (tid < LFR_D / 4) ((float4*)sa)[tid] = ((const float4*)alpha)[tid];
    }
    float sigw[LFR_K];
    #pragma unroll
    for (int k = 0; k < LFR_K; ++k) sigw[k] = 1.0f / (1.0f + __expf(-w[k]));
    __syncthreads();   // the ONLY block barrier

    const int r0 = (blockIdx.x * WPB + wib) * RPW;   // this wave's 16 rows

    // Stage issue for chunk ch into buffer b: 4 insts; inst i covers rows
    // i*4+qq; lane lands at LDS +lane*16 (forced linear). Pre-swizzled global
    // source: slot ss holds logical colf4 = ss ^ row, so the consume read
    // sx[..][rr][(qq*4+j4) ^ rr] (R6's measured-conflict-free pattern) sees
    // the right data.
    const float* xw = x + (size_t)r0 * LFR_D;   // wave's row block base

    #define STAGE(ch, b)                                                        \
        do {                                                                    \
            _Pragma("unroll")                                                   \
            for (int i_ = 0; i_ < 4; ++i_) {                                    \
                const int row_ = i_ * 4 + qq;                                   \
                const int cf4_ = ss ^ row_;                                     \
                GL2LDS(xw + (size_t)row_ * LFR_D + (ch) * 64 + cf4_ * 4,        \
                       &sx[wib][b][i_ * 4][0]);                                 \
            }                                                                   \
        } while (0)

    // ---- pass 1: prologue 2 chunks in flight, then consume/issue pipeline ----
    STAGE(0, 0);
    STAGE(1, 1);

    float dacc[LFR_K] = {0.f, 0.f, 0.f, 0.f, 0.f};

    #pragma unroll
    for (int ch = 0; ch < NCH; ++ch) {
        if (ch < NCH - 1) WAITVM4();     // chunk ch returned; ch+1 stays in flight
        else              WAITVM0();     // tail: drain last chunk
        const int b = ch & 1;
        #pragma unroll
        for (int j4 = 0; j4 < 4; ++j4) {
            const int col4 = qq * 4 + j4;
            float4 xv = sx[wib][b][rr][col4 ^ rr];
            float4 av = ((const float4*)&sa[ch * 64])[col4];   // broadcast read
            #pragma unroll
            for (int k = 0; k < LFR_K; ++k) {
                float4 cv = ((const float4*)&sc[k][ch * 64])[col4];
                float d0 = xv.x - cv.x, d1 = xv.y - cv.y;
                float d2 = xv.z - cv.z, d3 = xv.w - cv.w;
                dacc[k] = fmaf(av.x * d0, d0, dacc[k]);
                dacc[k] = fmaf(av.y * d1, d1, dacc[k]);
                dacc[k] = fmaf(av.z * d2, d2, dacc[k]);
                dacc[k] = fmaf(av.w * d3, d3, dacc[k]);
            }
        }
        if (ch + 2 < NCH) STAGE(ch + 2, b);   // refill the buffer just consumed
    }

    // ---- reduce the 4 d-quarters of each row (2 shuffle steps, once) ----
    #pragma unroll
    for (int k = 0; k < LFR_K; ++k) {
        dacc[k] += __shfl_xor(dacc[k], 16);
        dacc[k] += __shfl_xor(dacc[k], 32);
    }

    // ---- softmax per lane (every lane has its row's full dist) ----
    float e[LFR_K];
    float mx = dacc[0];
    #pragma unroll
    for (int k = 1; k < LFR_K; ++k) mx = fmaxf(mx, dacc[k]);
    float sum = 0.f;
    #pragma unroll
    for (int k = 0; k < LFR_K; ++k) { e[k] = __expf(dacc[k] - mx); sum += e[k]; }
    float inv = 1.0f / sum;
    #pragma unroll
    for (int k = 0; k < LFR_K; ++k) e[k] *= inv;

    // ---- map + pred: quarter-0 lane of each row writes (16 rows, 320B run) ----
    if (qq == 0) {
        float* mp = out_map + (size_t)(r0 + rr) * LFR_K;
        #pragma unroll
        for (int k = 0; k < LFR_K; ++k) mp[k] = e[k];
        float pr = e[0] * sigw[0];
        #pragma unroll
        for (int k = 1; k < LFR_K; ++k) pr = fmaf(e[k], sigw[k], pr);
        out_pred[r0 + rr] = pr;
    }

    // ---- pass 2: generate rec, stage through tile (buf 0), 1KB coalesced stores ----
    #pragma unroll
    for (int ch = 0; ch < NCH; ++ch) {
        LGKM0();                         // WAR: prior chunk's store-reads retired
        #pragma unroll
        for (int j4 = 0; j4 < 4; ++j4) {
            const int col4 = qq * 4 + j4;
            float4 c0 = ((const float4*)&sc[0][ch * 64])[col4];
            float4 rv;
            rv.x = e[0] * c0.x; rv.y = e[0] * c0.y;
            rv.z = e[0] * c0.z; rv.w = e[0] * c0.w;
            #pragma unroll
            for (int k = 1; k < LFR_K; ++k) {
                float4 cv = ((const float4*)&sc[k][ch * 64])[col4];
                rv.x = fmaf(e[k], cv.x, rv.x);
                rv.y = fmaf(e[k], cv.y, rv.y);
                rv.z = fmaf(e[k], cv.z, rv.z);
                rv.w = fmaf(e[k], cv.w, rv.w);
            }
            sx[wib][0][rr][col4 ^ rr] = rv;
        }
        LGKM0();                         // RAW: rec tile visible wave-wide
        #pragma unroll
        for (int i = 0; i < 4; ++i) {
            const int row = i * 4 + qq;
            float4 v = sx[wib][0][row][rr ^ row];
            *(float4*)(out_rec + (size_t)(r0 + row) * LFR_D + ch * 64 + rr * 4) = v;
        }
    }
}

extern "C" void kernel_launch(void* const* d_in, const int* in_sizes, int n_in,
                              void* d_out, int out_size, void* d_ws, size_t ws_size,
                              hipStream_t stream) {
    const float* x     = (const float*)d_in[0];   // (N, D)
    // d_in[1] = is_protected — unused by the reference computation
    const float* alpha = (const float*)d_in[2];   // (D,)
    const float* w     = (const float*)d_in[3];   // (K, 1)
    const float* cent  = (const float*)d_in[4];   // (K, D)

    float* out   = (float*)d_out;
    float* o_map = out;                                         // N*K
    float* o_rec = out + (size_t)LFR_N * LFR_K;                 // N*D
    float* o_prd = out + (size_t)LFR_N * LFR_K + (size_t)LFR_N * LFR_D;  // N

    // 1024 blocks x 256 threads; 44KB LDS/block -> 3 blocks/CU; per-wave
    // double-buffered global_load_lds pipeline, counted vmcnt (never 0 in loop).
    dim3 grid(BLOCKS), block(256);
    lfr_kernel<<<grid, block, 0, stream>>>(x, alpha, w, cent, o_map, o_rec, o_prd);
}